// Round 8
// baseline (825.257 us; speedup 1.0000x reference)
//
// GCNTox21 fused pipeline — MI355X/gfx950.  R8: k_msg6 = 4 channels/lane
// (wave covers 256ch => 2x VALU per edge-visit, half the e_h broadcast waves)
// + explicit 1-deep edge prefetch rotate (next-edge loads feed NEXT iter, so
// regalloc can't sink them) + 4 nodes/wave to amortize weight preload.
// k_gemm_pq2 (R7) reverted to R6's k_gemm_pq (pq2's 64-acc version regressed).
// Math (exact algebraic refactor):
//   P = h@w1[:,:256].T, Q = h@w1[:,256:512].T  (node GEMMs, MFMA bf16)
//   u_e = relu(P[dst] + Q[src] + e_h[e]@w1[:,512:].T + b1)
//   mean_u[n] = mean_{e:dst=n} u_e             (CSR over dst, built once)
//   h' = relu(BN(mean_u@w2.T + b2)), deg==0 rows -> BN(0)
//   out = sigmoid(mean_pool(h)@fc.T + fc_b)
#include <hip/hip_runtime.h>
#include <hip/hip_bf16.h>

typedef unsigned int  uint;
typedef unsigned short ushort;
typedef float  f32x2  __attribute__((ext_vector_type(2)));
typedef float  f32x4  __attribute__((ext_vector_type(4)));
typedef __bf16 bf16x8 __attribute__((ext_vector_type(8)));

#define DEV static __device__ __forceinline__

DEV float  b2f(ushort b){ return __uint_as_float(((uint)b) << 16); }
DEV float  lo2f(uint u){ return __uint_as_float(u << 16); }
DEV float  hi2f(uint u){ return __uint_as_float(u & 0xffff0000u); }
DEV ushort f2b(float f){           // RNE float->bf16
  uint u = __float_as_uint(f);
  u += 0x7fffu + ((u >> 16) & 1u);
  return (ushort)(u >> 16);
}
DEV uint pk2(float a, float b){ return (uint)f2b(a) | ((uint)f2b(b) << 16); }
DEV void unpack8(uint4 v, float* f){
  f[0]=lo2f(v.x); f[1]=hi2f(v.x); f[2]=lo2f(v.y); f[3]=hi2f(v.y);
  f[4]=lo2f(v.z); f[5]=hi2f(v.z); f[6]=lo2f(v.w); f[7]=hi2f(v.w);
}
DEV int ld_idx(const void* p, int flag, long long i){
  return flag ? ((const int*)p)[i] : (int)((const long long*)p)[i];
}
DEV int clampi(int v, int lo, int hi){ return v < lo ? lo : (v > hi ? hi : v); }

// ---------- merged probes ----------
__global__ void k_probes(const uint* __restrict__ ei, const uint* __restrict__ xw,
                         int* __restrict__ iflag, int* __restrict__ fflag){
  __shared__ int anyI, cntF;
  if (threadIdx.x == 0){ anyI = 0; cntF = 0; }
  __syncthreads();
  int li = 0, lc = 0;
  for (int i = threadIdx.x; i < 1024; i += 256){
    if (ei[2*i + 1] != 0u) li = 1;            // int64 => odd words all 0
    float f = fabsf(__uint_as_float(xw[i]));  // fp32 N(0,1) words decode sane
    if (f > 1e-6f && f < 1e6f) lc++;
  }
  if (li) atomicOr(&anyI, 1);
  atomicAdd(&cntF, lc);
  __syncthreads();
  if (threadIdx.x == 0){ *iflag = anyI; *fflag = (2*cntF > 1024) ? 1 : 0; }
}

// ---------- canonicalization ----------
__global__ __launch_bounds__(256) void k_canon(const void* __restrict__ src,
    const int* __restrict__ flag, int* __restrict__ out, int n){
  int i = blockIdx.x*256 + threadIdx.x;
  if (i >= n) return;
  out[i] = ld_idx(src, *flag, i);
}

struct CvtTab { const void* src[8]; ushort* dst[8]; int n[8]; int bstart[8]; int nseg; };
__global__ __launch_bounds__(256) void k_cvt_batch(CvtTab tab, const int* __restrict__ flag){
  int b = blockIdx.x;
  int s = tab.nseg - 1;
  for (int i = 1; i < tab.nseg; i++) if (b < tab.bstart[i]){ s = i - 1; break; }
  int rel = b - tab.bstart[s];
  const void* sp = tab.src[s];
  ushort* d = tab.dst[s];
  int f = *flag;
  int end = tab.n[s]; int cap = rel*8192 + 8192; if (cap < end) end = cap;
  for (int i = rel*8192 + threadIdx.x; i < end; i += 256)
    d[i] = f ? f2b(((const float*)sp)[i]) : ((const ushort*)sp)[i];
}

struct SmallTab { const void* src[24]; int doff[24]; int n[24]; };
__global__ __launch_bounds__(256) void k_cvt_small(SmallTab tab, const int* __restrict__ flag,
    ushort* __restrict__ base, int cnt){
  int b = blockIdx.x;
  if (b >= cnt) return;
  int f = *flag;
  const void* s = tab.src[b];
  ushort* d = base + tab.doff[b];
  for (int i = threadIdx.x; i < tab.n[b]; i += 256)
    d[i] = f ? f2b(((const float*)s)[i]) : ((const ushort*)s)[i];
}

// ---------- CSR build over dst ----------
__global__ __launch_bounds__(256) void k_count(const void* __restrict__ ei,
    const int* __restrict__ flag, int* __restrict__ cnt, int E, int N){
  int e = blockIdx.x*256 + threadIdx.x;
  if (e >= E) return;
  int d = clampi(ld_idx(ei, *flag, (long long)E + e), 0, N-1);
  atomicAdd(&cnt[d], 1);
}

__global__ __launch_bounds__(1024) void k_scan(const int* __restrict__ deg, int* __restrict__ rp, int n){
  __shared__ int part[1024];
  int t = threadIdx.x;
  int chunk = (n + 1023) >> 10;
  int base = t * chunk;
  int s = 0;
  for (int i = 0; i < chunk; i++){ int j = base + i; if (j < n) s += deg[j]; }
  part[t] = s;
  __syncthreads();
  for (int off = 1; off < 1024; off <<= 1){
    int v = (t >= off) ? part[t - off] : 0;
    __syncthreads();
    part[t] += v;
    __syncthreads();
  }
  int run = part[t] - s;
  for (int i = 0; i < chunk; i++){ int j = base + i; if (j < n){ rp[j] = run; run += deg[j]; } }
  if (t == 1023) rp[n] = part[1023];
}

__global__ __launch_bounds__(256) void k_fill(const void* __restrict__ ei,
    const int* __restrict__ flag, const int* __restrict__ rp, int* __restrict__ fill,
    int2* __restrict__ cpair, int E, int N){
  int e = blockIdx.x*256 + threadIdx.x;
  if (e >= E) return;
  int f = *flag;
  int s = clampi(ld_idx(ei, f, e), 0, N-1);
  int d = clampi(ld_idx(ei, f, (long long)E + e), 0, N-1);
  int pos = clampi(rp[d] + atomicAdd(&fill[d], 1), 0, E-1);
  cpair[pos] = make_int2(s, e);
}

// ---------- encoders ----------
__global__ __launch_bounds__(256) void k_edge_enc(const void* __restrict__ ea,
    const ushort* __restrict__ w, const ushort* __restrict__ b,
    const int* __restrict__ fflag, float* __restrict__ eh, int E){
  __shared__ float ws[128];
  __shared__ float bs[16];
  int t = threadIdx.x;
  if (t < 128) ws[t] = b2f(w[t]);
  if (t < 16)  bs[t] = b2f(b[t]);
  int f = *fflag;
  __syncthreads();
  int e = blockIdx.x*256 + t;
  if (e >= E) return;
  float a[8];
  if (f){
    const float4* ap = (const float4*)((const float*)ea + (size_t)e*8);
    float4 v0 = ap[0], v1 = ap[1];
    a[0]=v0.x; a[1]=v0.y; a[2]=v0.z; a[3]=v0.w;
    a[4]=v1.x; a[5]=v1.y; a[6]=v1.z; a[7]=v1.w;
  } else {
    uint4 av = *(const uint4*)((const ushort*)ea + (size_t)e*8);
    unpack8(av, a);
  }
  float o[16];
  #pragma unroll
  for (int c = 0; c < 16; c++){
    float s = bs[c];
    #pragma unroll
    for (int j = 0; j < 8; j++) s += a[j]*ws[c*8+j];
    o[c] = fmaxf(s, 0.f);
  }
  f32x4* op = (f32x4*)(eh + (size_t)e*16);
  #pragma unroll
  for (int q4 = 0; q4 < 4; q4++){
    f32x4 v = {o[q4*4+0], o[q4*4+1], o[q4*4+2], o[q4*4+3]};
    op[q4] = v;
  }
}

__global__ __launch_bounds__(256) void k_node_enc(const void* __restrict__ x,
    const ushort* __restrict__ w, const ushort* __restrict__ b,
    const int* __restrict__ fflag, ushort* __restrict__ h, int N){
  __shared__ float xs[32];
  int n = blockIdx.x, t = threadIdx.x;
  int f = *fflag;
  if (t < 32) xs[t] = f ? ((const float*)x)[(size_t)n*32 + t]
                        : b2f(((const ushort*)x)[(size_t)n*32 + t]);
  __syncthreads();
  const uint4* wp = (const uint4*)(w + (size_t)t*32);
  float s = b2f(b[t]);
  #pragma unroll
  for (int q4 = 0; q4 < 4; q4++){
    uint4 u = wp[q4];
    int k = q4*8;
    s += xs[k+0]*lo2f(u.x) + xs[k+1]*hi2f(u.x)
       + xs[k+2]*lo2f(u.y) + xs[k+3]*hi2f(u.y)
       + xs[k+4]*lo2f(u.z) + xs[k+5]*hi2f(u.z)
       + xs[k+6]*lo2f(u.w) + xs[k+7]*hi2f(u.w);
  }
  h[(size_t)n*256 + t] = f2b(fmaxf(s, 0.f));
}

// ---------- merged P/Q GEMM (R6 version), 32-row waves ----------
__global__ __launch_bounds__(256) void k_gemm_pq(const ushort* __restrict__ A,
    const ushort* __restrict__ w1, int M, int Nc,
    ushort* __restrict__ P, ushort* __restrict__ Q){
  const int l  = threadIdx.x & 63;
  const int wv = threadIdx.x >> 6;
  const int m0 = blockIdx.x*128 + wv*32;
  const int yc = Nc >> 6;
  const int isQ = (int)blockIdx.y >= yc;
  const int n0 = (isQ ? blockIdx.y - yc : blockIdx.y)*64;
  const ushort* W = w1 + (isQ ? 256 : 0);
  ushort* C = isQ ? Q : P;
  const int lr = l & 15;
  const int q  = l >> 4;
  int ar0 = m0 + lr;      if (ar0 >= M) ar0 = M - 1;
  int ar1 = m0 + 16 + lr; if (ar1 >= M) ar1 = M - 1;
  const ushort* Ap0 = A + (size_t)ar0*256 + q*8;
  const ushort* Ap1 = A + (size_t)ar1*256 + q*8;
  const ushort* Wp = W + (size_t)(n0 + lr)*528 + q*8;
  f32x4 acc[2][4];
  #pragma unroll
  for (int f = 0; f < 2; f++)
    #pragma unroll
    for (int nf = 0; nf < 4; nf++) acc[f][nf] = {0.f,0.f,0.f,0.f};
  #pragma unroll
  for (int k = 0; k < 256; k += 32){
    bf16x8 a0 = *(const bf16x8*)(Ap0 + k);
    bf16x8 a1 = *(const bf16x8*)(Ap1 + k);
    #pragma unroll
    for (int nf = 0; nf < 4; nf++){
      bf16x8 b = *(const bf16x8*)(Wp + (size_t)nf*16*528 + k);
      acc[0][nf] = __builtin_amdgcn_mfma_f32_16x16x32_bf16(a0, b, acc[0][nf], 0, 0, 0);
      acc[1][nf] = __builtin_amdgcn_mfma_f32_16x16x32_bf16(a1, b, acc[1][nf], 0, 0, 0);
    }
  }
  #pragma unroll
  for (int f = 0; f < 2; f++){
    #pragma unroll
    for (int nf = 0; nf < 4; nf++){
      int col = n0 + nf*16 + lr;
      #pragma unroll
      for (int r = 0; r < 4; r++){
        int row = m0 + 16*f + q*4 + r;
        if (row < M) C[(size_t)row*Nc + col] = f2b(acc[f][nf][r]);
      }
    }
  }
}

// GEMM + bias + deg-mask + eval-BN + relu, 32-row waves
__global__ __launch_bounds__(256) void k_gemm_bn(const ushort* __restrict__ A, int lda,
    const ushort* __restrict__ W, int ldb, int M, int Nc, int K,
    const ushort* __restrict__ bias, const ushort* __restrict__ g, const ushort* __restrict__ bb,
    const ushort* __restrict__ rm, const ushort* __restrict__ rv,
    const int* __restrict__ rp, ushort* __restrict__ H){
  const int l  = threadIdx.x & 63;
  const int wv = threadIdx.x >> 6;
  const int m0 = blockIdx.x*128 + wv*32;
  const int n0 = blockIdx.y*64;
  const int lr = l & 15;
  const int q  = l >> 4;
  int ar0 = m0 + lr;      if (ar0 >= M) ar0 = M - 1;
  int ar1 = m0 + 16 + lr; if (ar1 >= M) ar1 = M - 1;
  const ushort* Ap0 = A + (size_t)ar0*lda + q*8;
  const ushort* Ap1 = A + (size_t)ar1*lda + q*8;
  const ushort* Wp = W + (size_t)(n0 + lr)*ldb + q*8;
  f32x4 acc[2][4];
  #pragma unroll
  for (int f = 0; f < 2; f++)
    #pragma unroll
    for (int nf = 0; nf < 4; nf++) acc[f][nf] = {0.f,0.f,0.f,0.f};
  for (int k = 0; k < K; k += 32){
    bf16x8 a0 = *(const bf16x8*)(Ap0 + k);
    bf16x8 a1 = *(const bf16x8*)(Ap1 + k);
    #pragma unroll
    for (int nf = 0; nf < 4; nf++){
      bf16x8 b = *(const bf16x8*)(Wp + (size_t)nf*16*ldb + k);
      acc[0][nf] = __builtin_amdgcn_mfma_f32_16x16x32_bf16(a0, b, acc[0][nf], 0, 0, 0);
      acc[1][nf] = __builtin_amdgcn_mfma_f32_16x16x32_bf16(a1, b, acc[1][nf], 0, 0, 0);
    }
  }
  #pragma unroll
  for (int nf = 0; nf < 4; nf++){
    int col = n0 + nf*16 + lr;
    float bi = b2f(bias[col]);
    float sc = b2f(g[col]) * rsqrtf(b2f(rv[col]) + 1e-5f);
    float sh = b2f(bb[col]) - b2f(rm[col]) * sc;
    #pragma unroll
    for (int f = 0; f < 2; f++){
      #pragma unroll
      for (int r = 0; r < 4; r++){
        int row = m0 + 16*f + q*4 + r;
        if (row < M){
          float v = acc[f][nf][r] + bi;
          if (rp[row+1] - rp[row] == 0) v = 0.f;   // empty segment: mean is 0
          H[(size_t)row*Nc + col] = f2b(fmaxf(v*sc + sh, 0.f));
        }
      }
    }
  }
}

// ---------- per-node edge aggregation v6 ----------
// 4 channels/lane (wave = 256ch), 4 nodes/wave, explicit 1-deep edge prefetch.
// C=512: 8 nodes/block, wave wv: ch-half=wv&1, node parity s=wv>>1, n=nb+2k+s.
// C=256: 16 nodes/block, wave covers all ch, n=nb+4k+wv.
// No barriers/LDS.  MU may alias P (wave reads its P cells before writing MU).
template<int C>
__global__ __launch_bounds__(256) void k_msg6(const ushort* P, const ushort* __restrict__ Q,
    const float* __restrict__ eh, const ushort* __restrict__ w1, const ushort* __restrict__ b1,
    const int* __restrict__ rp, const int2* __restrict__ cpair,
    ushort* MU, int N){
  const int lane = threadIdx.x & 63;
  const int wv   = threadIdx.x >> 6;
  const int half   = (C == 512) ? (wv & 1)  : 0;
  const int sidx   = (C == 512) ? (wv >> 1) : wv;
  const int stride = (C == 512) ? 2 : 4;
  const int NPB    = stride * 4;
  const int c0 = half*256 + lane*4;
  f32x2 w01[16], w23[16];
  {
    float a0[16], a1[16], a2[16], a3[16];
    const uint4* wp0 = (const uint4*)(w1 + (size_t)(c0+0)*528 + 512);
    const uint4* wp1 = (const uint4*)(w1 + (size_t)(c0+1)*528 + 512);
    const uint4* wp2 = (const uint4*)(w1 + (size_t)(c0+2)*528 + 512);
    const uint4* wp3 = (const uint4*)(w1 + (size_t)(c0+3)*528 + 512);
    unpack8(wp0[0], a0); unpack8(wp0[1], a0+8);
    unpack8(wp1[0], a1); unpack8(wp1[1], a1+8);
    unpack8(wp2[0], a2); unpack8(wp2[1], a2+8);
    unpack8(wp3[0], a3); unpack8(wp3[1], a3+8);
    #pragma unroll
    for (int j = 0; j < 16; j++){
      w01[j].x = a0[j]; w01[j].y = a1[j];
      w23[j].x = a2[j]; w23[j].y = a3[j];
    }
  }
  uint2 bw = *(const uint2*)(b1 + c0);
  f32x2 b01 = { lo2f(bw.x), hi2f(bw.x) };
  f32x2 b23 = { lo2f(bw.y), hi2f(bw.y) };
  const int nb = blockIdx.x * NPB;
  for (int k = 0; k < 4; k++){
    int n = nb + stride*k + sidx;
    if (n >= N) continue;
    const int i0 = rp[n], i1 = rp[n+1];
    uint2 pw = *(const uint2*)(P + (size_t)n*C + c0);
    f32x2 pre01 = { lo2f(pw.x) + b01.x, hi2f(pw.x) + b01.y };
    f32x2 pre23 = { lo2f(pw.y) + b23.x, hi2f(pw.y) + b23.y };
    f32x2 acc01 = {0.f,0.f}, acc23 = {0.f,0.f};
    int i = i0;
    uint2 q; f32x4 e0, e1, e2, e3;
    if (i < i1){
      int2 p = cpair[i];
      q = *(const uint2*)(Q + (size_t)p.x*C + c0);
      const f32x4* ep = (const f32x4*)(eh + (size_t)p.y*16);
      e0 = ep[0]; e1 = ep[1]; e2 = ep[2]; e3 = ep[3];
    }
    while (i < i1){
      uint2 cq = q;
      f32x4 ce0 = e0, ce1 = e1, ce2 = e2, ce3 = e3;
      i++;
      if (i < i1){                       // prefetch NEXT edge (used next iter)
        int2 p = cpair[i];
        q = *(const uint2*)(Q + (size_t)p.x*C + c0);
        const f32x4* ep = (const f32x4*)(eh + (size_t)p.y*16);
        e0 = ep[0]; e1 = ep[1]; e2 = ep[2]; e3 = ep[3];
      }
      float ef[16] = {ce0.x,ce0.y,ce0.z,ce0.w, ce1.x,ce1.y,ce1.z,ce1.w,
                      ce2.x,ce2.y,ce2.z,ce2.w, ce3.x,ce3.y,ce3.z,ce3.w};
      f32x2 d01 = { pre01.x + lo2f(cq.x), pre01.y + hi2f(cq.x) };
      f32x2 d23 = { pre23.x + lo2f(cq.y), pre23.y + hi2f(cq.y) };
      #pragma unroll
      for (int j = 0; j < 16; j++){
        f32x2 ev = { ef[j], ef[j] };
        d01 += w01[j] * ev;
        d23 += w23[j] * ev;
      }
      acc01.x += fmaxf(d01.x, 0.f); acc01.y += fmaxf(d01.y, 0.f);
      acc23.x += fmaxf(d23.x, 0.f); acc23.y += fmaxf(d23.y, 0.f);
    }
    int cnt = i1 - i0;
    float inv = (cnt > 0) ? 1.f/(float)cnt : 0.f;
    uint2 outw = { pk2(acc01.x*inv, acc01.y*inv), pk2(acc23.x*inv, acc23.y*inv) };
    *(uint2*)(MU + (size_t)n*C + c0) = outw;
  }
}

// ---------- pooling + FC + sigmoid ----------
__global__ __launch_bounds__(128) void k_pool(const ushort* __restrict__ h, const int* __restrict__ batch,
    const ushort* __restrict__ fw, const ushort* __restrict__ fb,
    const int* __restrict__ fflag, void* __restrict__ out, int N){
  int g = blockIdx.x, t = threadIdx.x;
  int lo = 0, hi = N;
  while (lo < hi){ int mid = (lo+hi) >> 1; if (batch[mid] <  g) lo = mid+1; else hi = mid; }
  int s0 = lo;
  hi = N;
  while (lo < hi){ int mid = (lo+hi) >> 1; if (batch[mid] <= g) lo = mid+1; else hi = mid; }
  int s1 = lo;
  float s = 0.f;
  for (int i = s0; i < s1; i++) s += b2f(h[(size_t)i*128 + t]);
  int cnt = s1 - s0;
  __shared__ float ps[128];
  ps[t] = s / (float)(cnt > 0 ? cnt : 1);
  __syncthreads();
  if (t < 12){
    float z = b2f(fb[t]);
    for (int j = 0; j < 128; j++) z += ps[j]*b2f(fw[t*128 + j]);
    float r = 1.f/(1.f + expf(-z));
    if (*fflag) ((float*)out)[g*12 + t] = r;
    else        ((ushort*)out)[g*12 + t] = f2b(r);
  }
}

__global__ __launch_bounds__(256) void k_sentinel(ushort* __restrict__ out, int n){
  int i = blockIdx.x*256 + threadIdx.x;
  if (i < n) out[i] = 0x3F00;
}

extern "C" void kernel_launch(void* const* d_in, const int* in_sizes, int n_in,
                              void* d_out, int out_size, void* d_ws, size_t ws_size,
                              hipStream_t stream){
  const void* x_raw   = d_in[0];
  const void* ei_raw  = d_in[1];
  const void* ea_raw  = d_in[2];
  const void* ba_raw  = d_in[3];
  (void)n_in;

  const int N = in_sizes[3];        // 20000
  const int E = in_sizes[1] / 2;    // 200000
  const int G = out_size / 12;      // 512

  // ---- workspace plan ----
  char* base = (char*)d_ws;
  size_t off = 0;
  auto alloc = [&](size_t bytes)->char*{
    char* p = base + off;
    off = (off + bytes + 255) & ~(size_t)255;
    return p;
  };
  int* iflag    = (int*)alloc(256);
  int* fflag    = (int*)alloc(256);
  int* deg      = (int*)alloc((size_t)N*4);
  int* fill     = (int*)alloc((size_t)N*4);   // contiguous after deg (one memset)
  size_t memset_bytes = (size_t)((char*)fill - (char*)deg) + (size_t)N*4;
  int* rp       = (int*)alloc((size_t)(N+1)*4);
  int* batch2   = (int*)alloc((size_t)N*4);
  int2* cpair   = (int2*)alloc((size_t)E*8);
  ushort* new_c = (ushort*)alloc(8192*2);
  ushort* w1c[3], *w2c[3];
  const int w1n[3] = {512*528, 512*528, 256*528};
  const int w2n[3] = {256*512, 256*512, 128*256};
  for (int i = 0; i < 3; i++) w1c[i] = (ushort*)alloc((size_t)w1n[i]*2);
  for (int i = 0; i < 3; i++) w2c[i] = (ushort*)alloc((size_t)w2n[i]*2);
  ushort* smallp = (ushort*)alloc(8192*2);
  float*  e_h32 = (float*)alloc((size_t)E*16*4);    // 12.8 MB, pre-unpacked f32
  ushort* h     = (ushort*)alloc((size_t)N*256*2);
  ushort* Q     = (ushort*)alloc((size_t)N*512*2);
  ushort* PM    = (ushort*)alloc((size_t)N*512*2);

  if (off > ws_size){
    k_sentinel<<<(out_size + 255)/256, 256, 0, stream>>>((ushort*)d_out, out_size);
    return;
  }

  // ---- probes + CSR ----
  k_probes<<<1, 256, 0, stream>>>((const uint*)ei_raw, (const uint*)x_raw, iflag, fflag);
  k_canon<<<(N + 255)/256, 256, 0, stream>>>(ba_raw, iflag, batch2, N);
  hipMemsetAsync(deg, 0, memset_bytes, stream);
  k_count<<<(E + 255)/256, 256, 0, stream>>>(ei_raw, iflag, deg, E, N);
  k_scan<<<1, 1024, 0, stream>>>(deg, rp, N);
  k_fill<<<(E + 255)/256, 256, 0, stream>>>(ei_raw, iflag, rp, fill, cpair, E, N);

  // ---- batched weight conversion (w1 x3, w2 x3, ne_w) ----
  CvtTab ct; ct.nseg = 7;
  const void* csrcs[7] = {d_in[8], d_in[16], d_in[24], d_in[10], d_in[18], d_in[26], d_in[6]};
  ushort* cdsts[7]     = {w1c[0],  w1c[1],   w1c[2],   w2c[0],   w2c[1],   w2c[2],   new_c};
  const int cns[7]     = {w1n[0],  w1n[1],   w1n[2],   w2n[0],   w2n[1],   w2n[2],   8192};
  int bacc = 0;
  for (int i = 0; i < 7; i++){
    ct.src[i] = csrcs[i]; ct.dst[i] = cdsts[i]; ct.n[i] = cns[i];
    ct.bstart[i] = bacc; bacc += (cns[i] + 8191)/8192;
  }
  k_cvt_batch<<<bacc, 256, 0, stream>>>(ct, fflag);

  // ---- small vectors packed ----
  SmallTab tab;
  int scount = 0, spos = 0;
  auto addsmall = [&](int di, int n)->int{
    int p = spos;
    tab.src[scount] = d_in[di]; tab.doff[scount] = spos; tab.n[scount] = n;
    spos += n; scount++;
    return p;
  };
  int pos_eew  = addsmall(4, 128);
  int pos_eeb  = addsmall(5, 16);
  int pos_neb  = addsmall(7, 256);
  int pos_b1[3], pos_b2[3], pos_g[3], pos_bb[3], pos_m[3], pos_v[3];
  const int b1n[3] = {512,512,256}, b2n[3] = {256,256,128}, bnn[3] = {256,256,128};
  for (int i = 0; i < 3; i++){
    int di = 8 + 8*i;
    pos_b1[i] = addsmall(di+1, b1n[i]);
    pos_b2[i] = addsmall(di+3, b2n[i]);
    pos_g[i]  = addsmall(di+4, bnn[i]);
    pos_bb[i] = addsmall(di+5, bnn[i]);
    pos_m[i]  = addsmall(di+6, bnn[i]);
    pos_v[i]  = addsmall(di+7, bnn[i]);
  }
  int pos_fcw = addsmall(32, 12*128);
  int pos_fcb = addsmall(33, 12);
  k_cvt_small<<<scount, 256, 0, stream>>>(tab, fflag, smallp, scount);

  // ---- encoders ----
  k_edge_enc<<<(E + 255)/256, 256, 0, stream>>>(ea_raw, smallp + pos_eew, smallp + pos_eeb, fflag, e_h32, E);
  k_node_enc<<<N, 256, 0, stream>>>(x_raw, new_c, smallp + pos_neb, fflag, h, N);

  // ---- 3 conv layers ----
  const int Cch[3] = {512, 512, 256};
  const int Od[3]  = {256, 256, 128};
  for (int i = 0; i < 3; i++){
    dim3 g1((N + 127)/128, 2*(Cch[i]/64));
    k_gemm_pq<<<g1, 256, 0, stream>>>(h, w1c[i], N, Cch[i], PM, Q);
    if (i < 2){
      dim3 gm((N + 7)/8);
      k_msg6<512><<<gm, 256, 0, stream>>>(PM, Q, e_h32, w1c[i], smallp + pos_b1[i], rp, cpair, PM, N);
    } else {
      dim3 gm((N + 15)/16);
      k_msg6<256><<<gm, 256, 0, stream>>>(PM, Q, e_h32, w1c[i], smallp + pos_b1[i], rp, cpair, PM, N);
    }
    dim3 g2((N + 127)/128, Od[i]/64);
    k_gemm_bn<<<g2, 256, 0, stream>>>(PM, Cch[i], w2c[i], Cch[i], N, Od[i], Cch[i],
                                      smallp + pos_b2[i], smallp + pos_g[i], smallp + pos_bb[i],
                                      smallp + pos_m[i],  smallp + pos_v[i], rp, h);
  }

  // ---- mean pool + FC + sigmoid ----
  k_pool<<<G, 128, 0, stream>>>(h, batch2, smallp + pos_fcw, smallp + pos_fcb, fflag, d_out, N);
}

// Round 9
// 533.359 us; speedup vs baseline: 1.5473x; 1.5473x over previous
//
// GCNTox21 fused pipeline — MI355X/gfx950.  R9: k_msg reverted to R6's k_msg4
// (70us known-good; R7/R8 variants regressed — wave count is the resource).
// GEMMs rewritten as 128x128-tile LDS kernels: global_load_lds width=16
// staging (lane-contiguous), ds_read_b128 fragments, 16 MFMA / 10 ds_read per
// wave-step (m97 ladder recipe).  [row][4x16B-chunk] LDS layout is naturally
// bank-balanced (quarter-wave k-split covers all 8 banksets) — no swizzle.
// Math (exact algebraic refactor):
//   P = h@w1[:,:256].T, Q = h@w1[:,256:512].T  (node GEMMs, MFMA bf16)
//   u_e = relu(P[dst] + Q[src] + e_h[e]@w1[:,512:].T + b1)
//   mean_u[n] = mean_{e:dst=n} u_e             (CSR over dst, built once)
//   h' = relu(BN(mean_u@w2.T + b2)), deg==0 rows -> BN(0)
//   out = sigmoid(mean_pool(h)@fc.T + fc_b)
#include <hip/hip_runtime.h>
#include <hip/hip_bf16.h>

typedef unsigned int  uint;
typedef unsigned short ushort;
typedef float  f32x2  __attribute__((ext_vector_type(2)));
typedef float  f32x4  __attribute__((ext_vector_type(4)));
typedef __bf16 bf16x8 __attribute__((ext_vector_type(8)));

#define DEV static __device__ __forceinline__

DEV float  b2f(ushort b){ return __uint_as_float(((uint)b) << 16); }
DEV float  lo2f(uint u){ return __uint_as_float(u << 16); }
DEV float  hi2f(uint u){ return __uint_as_float(u & 0xffff0000u); }
DEV ushort f2b(float f){           // RNE float->bf16
  uint u = __float_as_uint(f);
  u += 0x7fffu + ((u >> 16) & 1u);
  return (ushort)(u >> 16);
}
DEV uint pk2(float a, float b){ return (uint)f2b(a) | ((uint)f2b(b) << 16); }
DEV void unpack8(uint4 v, float* f){
  f[0]=lo2f(v.x); f[1]=hi2f(v.x); f[2]=lo2f(v.y); f[3]=hi2f(v.y);
  f[4]=lo2f(v.z); f[5]=hi2f(v.z); f[6]=lo2f(v.w); f[7]=hi2f(v.w);
}
DEV int ld_idx(const void* p, int flag, long long i){
  return flag ? ((const int*)p)[i] : (int)((const long long*)p)[i];
}
DEV int clampi(int v, int lo, int hi){ return v < lo ? lo : (v > hi ? hi : v); }

// async 16B global -> LDS (DMA, no VGPR round-trip).  LDS dest must be
// wave-uniform base + lane*16 — our flat mapping guarantees it.
DEV void ld16(const ushort* g, ushort* l){
  __builtin_amdgcn_global_load_lds(
      (const __attribute__((address_space(1))) void*)g,
      (__attribute__((address_space(3))) void*)l, 16, 0, 0);
}

// ---------- merged probes ----------
__global__ void k_probes(const uint* __restrict__ ei, const uint* __restrict__ xw,
                         int* __restrict__ iflag, int* __restrict__ fflag){
  __shared__ int anyI, cntF;
  if (threadIdx.x == 0){ anyI = 0; cntF = 0; }
  __syncthreads();
  int li = 0, lc = 0;
  for (int i = threadIdx.x; i < 1024; i += 256){
    if (ei[2*i + 1] != 0u) li = 1;            // int64 => odd words all 0
    float f = fabsf(__uint_as_float(xw[i]));  // fp32 N(0,1) words decode sane
    if (f > 1e-6f && f < 1e6f) lc++;
  }
  if (li) atomicOr(&anyI, 1);
  atomicAdd(&cntF, lc);
  __syncthreads();
  if (threadIdx.x == 0){ *iflag = anyI; *fflag = (2*cntF > 1024) ? 1 : 0; }
}

// ---------- canonicalization ----------
__global__ __launch_bounds__(256) void k_canon(const void* __restrict__ src,
    const int* __restrict__ flag, int* __restrict__ out, int n){
  int i = blockIdx.x*256 + threadIdx.x;
  if (i >= n) return;
  out[i] = ld_idx(src, *flag, i);
}

struct CvtTab { const void* src[8]; ushort* dst[8]; int n[8]; int bstart[8]; int nseg; };
__global__ __launch_bounds__(256) void k_cvt_batch(CvtTab tab, const int* __restrict__ flag){
  int b = blockIdx.x;
  int s = tab.nseg - 1;
  for (int i = 1; i < tab.nseg; i++) if (b < tab.bstart[i]){ s = i - 1; break; }
  int rel = b - tab.bstart[s];
  const void* sp = tab.src[s];
  ushort* d = tab.dst[s];
  int f = *flag;
  int end = tab.n[s]; int cap = rel*8192 + 8192; if (cap < end) end = cap;
  for (int i = rel*8192 + threadIdx.x; i < end; i += 256)
    d[i] = f ? f2b(((const float*)sp)[i]) : ((const ushort*)sp)[i];
}

struct SmallTab { const void* src[24]; int doff[24]; int n[24]; };
__global__ __launch_bounds__(256) void k_cvt_small(SmallTab tab, const int* __restrict__ flag,
    ushort* __restrict__ base, int cnt){
  int b = blockIdx.x;
  if (b >= cnt) return;
  int f = *flag;
  const void* s = tab.src[b];
  ushort* d = base + tab.doff[b];
  for (int i = threadIdx.x; i < tab.n[b]; i += 256)
    d[i] = f ? f2b(((const float*)s)[i]) : ((const ushort*)s)[i];
}

// ---------- CSR build over dst ----------
__global__ __launch_bounds__(256) void k_count(const void* __restrict__ ei,
    const int* __restrict__ flag, int* __restrict__ cnt, int E, int N){
  int e = blockIdx.x*256 + threadIdx.x;
  if (e >= E) return;
  int d = clampi(ld_idx(ei, *flag, (long long)E + e), 0, N-1);
  atomicAdd(&cnt[d], 1);
}

__global__ __launch_bounds__(1024) void k_scan(const int* __restrict__ deg, int* __restrict__ rp, int n){
  __shared__ int part[1024];
  int t = threadIdx.x;
  int chunk = (n + 1023) >> 10;
  int base = t * chunk;
  int s = 0;
  for (int i = 0; i < chunk; i++){ int j = base + i; if (j < n) s += deg[j]; }
  part[t] = s;
  __syncthreads();
  for (int off = 1; off < 1024; off <<= 1){
    int v = (t >= off) ? part[t - off] : 0;
    __syncthreads();
    part[t] += v;
    __syncthreads();
  }
  int run = part[t] - s;
  for (int i = 0; i < chunk; i++){ int j = base + i; if (j < n){ rp[j] = run; run += deg[j]; } }
  if (t == 1023) rp[n] = part[1023];
}

__global__ __launch_bounds__(256) void k_fill(const void* __restrict__ ei,
    const int* __restrict__ flag, const int* __restrict__ rp, int* __restrict__ fill,
    int2* __restrict__ cpair, int E, int N){
  int e = blockIdx.x*256 + threadIdx.x;
  if (e >= E) return;
  int f = *flag;
  int s = clampi(ld_idx(ei, f, e), 0, N-1);
  int d = clampi(ld_idx(ei, f, (long long)E + e), 0, N-1);
  int pos = clampi(rp[d] + atomicAdd(&fill[d], 1), 0, E-1);
  cpair[pos] = make_int2(s, e);
}

// ---------- encoders ----------
__global__ __launch_bounds__(256) void k_edge_enc(const void* __restrict__ ea,
    const ushort* __restrict__ w, const ushort* __restrict__ b,
    const int* __restrict__ fflag, float* __restrict__ eh, int E){
  __shared__ float ws[128];
  __shared__ float bs[16];
  int t = threadIdx.x;
  if (t < 128) ws[t] = b2f(w[t]);
  if (t < 16)  bs[t] = b2f(b[t]);
  int f = *fflag;
  __syncthreads();
  int e = blockIdx.x*256 + t;
  if (e >= E) return;
  float a[8];
  if (f){
    const float4* ap = (const float4*)((const float*)ea + (size_t)e*8);
    float4 v0 = ap[0], v1 = ap[1];
    a[0]=v0.x; a[1]=v0.y; a[2]=v0.z; a[3]=v0.w;
    a[4]=v1.x; a[5]=v1.y; a[6]=v1.z; a[7]=v1.w;
  } else {
    uint4 av = *(const uint4*)((const ushort*)ea + (size_t)e*8);
    unpack8(av, a);
  }
  float o[16];
  #pragma unroll
  for (int c = 0; c < 16; c++){
    float s = bs[c];
    #pragma unroll
    for (int j = 0; j < 8; j++) s += a[j]*ws[c*8+j];
    o[c] = fmaxf(s, 0.f);
  }
  f32x4* op = (f32x4*)(eh + (size_t)e*16);
  #pragma unroll
  for (int q4 = 0; q4 < 4; q4++){
    f32x4 v = {o[q4*4+0], o[q4*4+1], o[q4*4+2], o[q4*4+3]};
    op[q4] = v;
  }
}

__global__ __launch_bounds__(256) void k_node_enc(const void* __restrict__ x,
    const ushort* __restrict__ w, const ushort* __restrict__ b,
    const int* __restrict__ fflag, ushort* __restrict__ h, int N){
  __shared__ float xs[32];
  int n = blockIdx.x, t = threadIdx.x;
  int f = *fflag;
  if (t < 32) xs[t] = f ? ((const float*)x)[(size_t)n*32 + t]
                        : b2f(((const ushort*)x)[(size_t)n*32 + t]);
  __syncthreads();
  const uint4* wp = (const uint4*)(w + (size_t)t*32);
  float s = b2f(b[t]);
  #pragma unroll
  for (int q4 = 0; q4 < 4; q4++){
    uint4 u = wp[q4];
    int k = q4*8;
    s += xs[k+0]*lo2f(u.x) + xs[k+1]*hi2f(u.x)
       + xs[k+2]*lo2f(u.y) + xs[k+3]*hi2f(u.y)
       + xs[k+4]*lo2f(u.z) + xs[k+5]*hi2f(u.z)
       + xs[k+6]*lo2f(u.w) + xs[k+7]*hi2f(u.w);
  }
  h[(size_t)n*256 + t] = f2b(fmaxf(s, 0.f));
}

// ---------- LDS-staged 128x128 GEMM: P/Q producer ----------
// Block: 128 rows x 128 cols, K=256 in 32-steps.  Wave wv: rows [32wv, +32).
// LDS tile layout: [row][4 chunks of 16B] (row stride 64B) — bank-balanced.
__global__ __launch_bounds__(256) void k_gemm_pq_lds(const ushort* __restrict__ A,
    const ushort* __restrict__ w1, int M, int Nc,
    ushort* __restrict__ P, ushort* __restrict__ Q){
  __shared__ ushort As[128*32];
  __shared__ ushort Bs[128*32];
  const int t = threadIdx.x;
  const int lane = t & 63;
  const int wv = t >> 6;
  const int m0 = blockIdx.x*128;
  const int yc = Nc >> 7;
  const int isQ = (int)blockIdx.y >= yc;
  const int n0 = (isQ ? blockIdx.y - yc : blockIdx.y)*128;
  const ushort* W = w1 + (isQ ? 256 : 0);
  ushort* C = isQ ? Q : P;
  const int lr = lane & 15;
  const int qq = lane >> 4;
  // pre-compute staging rows (flat = i*256+t; row=flat>>2, chunk=flat&3)
  int srow0 = t >> 2,        sq0 = t & 3;
  int srow1 = (256 + t) >> 2, sq1 = t & 3;          // +256 => row += 64
  int ga0 = m0 + srow0; if (ga0 >= M) ga0 = M - 1;
  int ga1 = m0 + srow1; if (ga1 >= M) ga1 = M - 1;
  f32x4 acc[2][8];
  #pragma unroll
  for (int f = 0; f < 2; f++)
    #pragma unroll
    for (int j = 0; j < 8; j++) acc[f][j] = {0.f,0.f,0.f,0.f};
  for (int k0 = 0; k0 < 256; k0 += 32){
    ld16(A + (size_t)ga0*256 + k0 + sq0*8, &As[(size_t)t*8]);
    ld16(A + (size_t)ga1*256 + k0 + sq1*8, &As[(size_t)(256+t)*8]);
    ld16(W + (size_t)(n0 + srow0)*528 + k0 + sq0*8, &Bs[(size_t)t*8]);
    ld16(W + (size_t)(n0 + srow1)*528 + k0 + sq1*8, &Bs[(size_t)(256+t)*8]);
    __syncthreads();
    bf16x8 a0 = *(const bf16x8*)&As[(wv*32 + lr)*32 + qq*8];
    bf16x8 a1 = *(const bf16x8*)&As[(wv*32 + 16 + lr)*32 + qq*8];
    #pragma unroll
    for (int j = 0; j < 8; j++){
      bf16x8 b = *(const bf16x8*)&Bs[(j*16 + lr)*32 + qq*8];
      acc[0][j] = __builtin_amdgcn_mfma_f32_16x16x32_bf16(a0, b, acc[0][j], 0, 0, 0);
      acc[1][j] = __builtin_amdgcn_mfma_f32_16x16x32_bf16(a1, b, acc[1][j], 0, 0, 0);
    }
    __syncthreads();
  }
  #pragma unroll
  for (int f = 0; f < 2; f++){
    #pragma unroll
    for (int r = 0; r < 4; r++){
      int row = m0 + wv*32 + f*16 + qq*4 + r;
      if (row >= M) continue;
      #pragma unroll
      for (int j = 0; j < 8; j++)
        C[(size_t)row*Nc + n0 + j*16 + lr] = f2b(acc[f][j][r]);
    }
  }
}

// ---------- LDS-staged 128x128 GEMM + bias + deg-mask + BN + relu ----------
__global__ __launch_bounds__(256) void k_gemm_bn_lds(const ushort* __restrict__ A, int lda,
    const ushort* __restrict__ W, int ldb, int M, int Nc, int K,
    const ushort* __restrict__ bias, const ushort* __restrict__ g, const ushort* __restrict__ bb,
    const ushort* __restrict__ rm, const ushort* __restrict__ rv,
    const int* __restrict__ rp, ushort* __restrict__ H){
  __shared__ ushort As[128*32];
  __shared__ ushort Bs[128*32];
  const int t = threadIdx.x;
  const int lane = t & 63;
  const int wv = t >> 6;
  const int m0 = blockIdx.x*128;
  const int n0 = blockIdx.y*128;
  const int lr = lane & 15;
  const int qq = lane >> 4;
  int srow0 = t >> 2,         sq0 = t & 3;
  int srow1 = (256 + t) >> 2, sq1 = t & 3;
  int ga0 = m0 + srow0; if (ga0 >= M) ga0 = M - 1;
  int ga1 = m0 + srow1; if (ga1 >= M) ga1 = M - 1;
  f32x4 acc[2][8];
  #pragma unroll
  for (int f = 0; f < 2; f++)
    #pragma unroll
    for (int j = 0; j < 8; j++) acc[f][j] = {0.f,0.f,0.f,0.f};
  for (int k0 = 0; k0 < K; k0 += 32){
    ld16(A + (size_t)ga0*lda + k0 + sq0*8, &As[(size_t)t*8]);
    ld16(A + (size_t)ga1*lda + k0 + sq1*8, &As[(size_t)(256+t)*8]);
    ld16(W + (size_t)(n0 + srow0)*ldb + k0 + sq0*8, &Bs[(size_t)t*8]);
    ld16(W + (size_t)(n0 + srow1)*ldb + k0 + sq1*8, &Bs[(size_t)(256+t)*8]);
    __syncthreads();
    bf16x8 a0 = *(const bf16x8*)&As[(wv*32 + lr)*32 + qq*8];
    bf16x8 a1 = *(const bf16x8*)&As[(wv*32 + 16 + lr)*32 + qq*8];
    #pragma unroll
    for (int j = 0; j < 8; j++){
      bf16x8 b = *(const bf16x8*)&Bs[(j*16 + lr)*32 + qq*8];
      acc[0][j] = __builtin_amdgcn_mfma_f32_16x16x32_bf16(a0, b, acc[0][j], 0, 0, 0);
      acc[1][j] = __builtin_amdgcn_mfma_f32_16x16x32_bf16(a1, b, acc[1][j], 0, 0, 0);
    }
    __syncthreads();
  }
  // per-col BN constants for this thread's 8 cols
  float bi[8], sc[8], sh[8];
  #pragma unroll
  for (int j = 0; j < 8; j++){
    int col = n0 + j*16 + lr;
    bi[j] = b2f(bias[col]);
    sc[j] = b2f(g[col]) * rsqrtf(b2f(rv[col]) + 1e-5f);
    sh[j] = b2f(bb[col]) - b2f(rm[col]) * sc[j];
  }
  #pragma unroll
  for (int f = 0; f < 2; f++){
    #pragma unroll
    for (int r = 0; r < 4; r++){
      int row = m0 + wv*32 + f*16 + qq*4 + r;
      if (row >= M) continue;
      int empty = (rp[row+1] - rp[row] == 0);
      #pragma unroll
      for (int j = 0; j < 8; j++){
        float v = acc[f][j][r] + bi[j];
        if (empty) v = 0.f;
        H[(size_t)row*Nc + n0 + j*16 + lr] = f2b(fmaxf(v*sc[j] + sh[j], 0.f));
      }
    }
  }
}

// ---------- per-node edge aggregation (R6 k_msg4, known-good 70us) ----------
// 4 nodes/block, NO barriers/LDS; thread t owns channels {2t,2t+1}.
// 2-edge unrolled inner loop (ILP).  MU may alias P (read-before-write).
template<int C>
__global__ __launch_bounds__(256) void k_msg4(const ushort* P, const ushort* __restrict__ Q,
    const float* __restrict__ eh, const ushort* __restrict__ w1, const ushort* __restrict__ b1,
    const int* __restrict__ rp, const int2* __restrict__ cpair,
    ushort* MU, int N){
  int t = threadIdx.x;
  int c0 = t*2;
  f32x2 wc[16];
  {
    float a0[16], a1[16];
    const uint4* wp0 = (const uint4*)(w1 + (size_t)c0*528 + 512);
    const uint4* wp1 = (const uint4*)(w1 + (size_t)(c0+1)*528 + 512);
    unpack8(wp0[0], a0); unpack8(wp0[1], a0+8);
    unpack8(wp1[0], a1); unpack8(wp1[1], a1+8);
    #pragma unroll
    for (int j = 0; j < 16; j++){ wc[j].x = a0[j]; wc[j].y = a1[j]; }
  }
  uint bw = *(const uint*)(b1 + c0);
  f32x2 b1v = { lo2f(bw), hi2f(bw) };
  int nb = blockIdx.x*4;
  int ne = nb + 4; if (ne > N) ne = N;
  for (int n = nb; n < ne; n++){
    const int i0 = rp[n], i1 = rp[n+1];
    uint pw = *(const uint*)(P + (size_t)n*C + c0);
    f32x2 pre = { lo2f(pw) + b1v.x, hi2f(pw) + b1v.y };
    f32x2 acc0 = {0.f, 0.f}, acc1 = {0.f, 0.f};
    int i = i0;
    for (; i + 2 <= i1; i += 2){
      int2 p0 = cpair[i];
      int2 p1 = cpair[i+1];
      uint qw0 = *(const uint*)(Q + (size_t)p0.x*C + c0);
      uint qw1 = *(const uint*)(Q + (size_t)p1.x*C + c0);
      const f32x4* e0p = (const f32x4*)(eh + (size_t)p0.y*16);
      const f32x4* e1p = (const f32x4*)(eh + (size_t)p1.y*16);
      f32x4 ea0 = e0p[0], ea1 = e0p[1], ea2 = e0p[2], ea3 = e0p[3];
      f32x4 eb0 = e1p[0], eb1 = e1p[1], eb2 = e1p[2], eb3 = e1p[3];
      float ef0[16] = {ea0.x,ea0.y,ea0.z,ea0.w, ea1.x,ea1.y,ea1.z,ea1.w,
                       ea2.x,ea2.y,ea2.z,ea2.w, ea3.x,ea3.y,ea3.z,ea3.w};
      float ef1[16] = {eb0.x,eb0.y,eb0.z,eb0.w, eb1.x,eb1.y,eb1.z,eb1.w,
                       eb2.x,eb2.y,eb2.z,eb2.w, eb3.x,eb3.y,eb3.z,eb3.w};
      f32x2 d0 = { pre.x + lo2f(qw0), pre.y + hi2f(qw0) };
      f32x2 d1 = { pre.x + lo2f(qw1), pre.y + hi2f(qw1) };
      #pragma unroll
      for (int j = 0; j < 16; j++){
        f32x2 e0v = {ef0[j], ef0[j]};
        f32x2 e1v = {ef1[j], ef1[j]};
        d0 += wc[j] * e0v;
        d1 += wc[j] * e1v;
      }
      acc0.x += fmaxf(d0.x, 0.f); acc0.y += fmaxf(d0.y, 0.f);
      acc1.x += fmaxf(d1.x, 0.f); acc1.y += fmaxf(d1.y, 0.f);
    }
    if (i < i1){
      int2 p0 = cpair[i];
      uint qw0 = *(const uint*)(Q + (size_t)p0.x*C + c0);
      const f32x4* e0p = (const f32x4*)(eh + (size_t)p0.y*16);
      f32x4 ea0 = e0p[0], ea1 = e0p[1], ea2 = e0p[2], ea3 = e0p[3];
      float ef0[16] = {ea0.x,ea0.y,ea0.z,ea0.w, ea1.x,ea1.y,ea1.z,ea1.w,
                       ea2.x,ea2.y,ea2.z,ea2.w, ea3.x,ea3.y,ea3.z,ea3.w};
      f32x2 d0 = { pre.x + lo2f(qw0), pre.y + hi2f(qw0) };
      #pragma unroll
      for (int j = 0; j < 16; j++){
        f32x2 e0v = {ef0[j], ef0[j]};
        d0 += wc[j] * e0v;
      }
      acc0.x += fmaxf(d0.x, 0.f); acc0.y += fmaxf(d0.y, 0.f);
    }
    int cnt = i1 - i0;
    float inv = (cnt > 0) ? 1.f/(float)cnt : 0.f;
    *(uint*)(MU + (size_t)n*C + c0) = pk2((acc0.x + acc1.x)*inv, (acc0.y + acc1.y)*inv);
  }
}

// ---------- pooling + FC + sigmoid ----------
__global__ __launch_bounds__(128) void k_pool(const ushort* __restrict__ h, const int* __restrict__ batch,
    const ushort* __restrict__ fw, const ushort* __restrict__ fb,
    const int* __restrict__ fflag, void* __restrict__ out, int N){
  int g = blockIdx.x, t = threadIdx.x;
  int lo = 0, hi = N;
  while (lo < hi){ int mid = (lo+hi) >> 1; if (batch[mid] <  g) lo = mid+1; else hi = mid; }
  int s0 = lo;
  hi = N;
  while (lo < hi){ int mid = (lo+hi) >> 1; if (batch[mid] <= g) lo = mid+1; else hi = mid; }
  int s1 = lo;
  float s = 0.f;
  for (int i = s0; i < s1; i++) s += b2f(h[(size_t)i*128 + t]);
  int cnt = s1 - s0;
  __shared__ float ps[128];
  ps[t] = s / (float)(cnt > 0 ? cnt : 1);
  __syncthreads();
  if (t < 12){
    float z = b2f(fb[t]);
    for (int j = 0; j < 128; j++) z += ps[j]*b2f(fw[t*128 + j]);
    float r = 1.f/(1.f + expf(-z));
    if (*fflag) ((float*)out)[g*12 + t] = r;
    else        ((ushort*)out)[g*12 + t] = f2b(r);
  }
}

__global__ __launch_bounds__(256) void k_sentinel(ushort* __restrict__ out, int n){
  int i = blockIdx.x*256 + threadIdx.x;
  if (i < n) out[i] = 0x3F00;
}

extern "C" void kernel_launch(void* const* d_in, const int* in_sizes, int n_in,
                              void* d_out, int out_size, void* d_ws, size_t ws_size,
                              hipStream_t stream){
  const void* x_raw   = d_in[0];
  const void* ei_raw  = d_in[1];
  const void* ea_raw  = d_in[2];
  const void* ba_raw  = d_in[3];
  (void)n_in;

  const int N = in_sizes[3];        // 20000
  const int E = in_sizes[1] / 2;    // 200000
  const int G = out_size / 12;      // 512

  // ---- workspace plan ----
  char* base = (char*)d_ws;
  size_t off = 0;
  auto alloc = [&](size_t bytes)->char*{
    char* p = base + off;
    off = (off + bytes + 255) & ~(size_t)255;
    return p;
  };
  int* iflag    = (int*)alloc(256);
  int* fflag    = (int*)alloc(256);
  int* deg      = (int*)alloc((size_t)N*4);
  int* fill     = (int*)alloc((size_t)N*4);   // contiguous after deg (one memset)
  size_t memset_bytes = (size_t)((char*)fill - (char*)deg) + (size_t)N*4;
  int* rp       = (int*)alloc((size_t)(N+1)*4);
  int* batch2   = (int*)alloc((size_t)N*4);
  int2* cpair   = (int2*)alloc((size_t)E*8);
  ushort* new_c = (ushort*)alloc(8192*2);
  ushort* w1c[3], *w2c[3];
  const int w1n[3] = {512*528, 512*528, 256*528};
  const int w2n[3] = {256*512, 256*512, 128*256};
  for (int i = 0; i < 3; i++) w1c[i] = (ushort*)alloc((size_t)w1n[i]*2);
  for (int i = 0; i < 3; i++) w2c[i] = (ushort*)alloc((size_t)w2n[i]*2);
  ushort* smallp = (ushort*)alloc(8192*2);
  float*  e_h32 = (float*)alloc((size_t)E*16*4);    // 12.8 MB, pre-unpacked f32
  ushort* h     = (ushort*)alloc((size_t)N*256*2);
  ushort* Q     = (ushort*)alloc((size_t)N*512*2);
  ushort* PM    = (ushort*)alloc((size_t)N*512*2);

  if (off > ws_size){
    k_sentinel<<<(out_size + 255)/256, 256, 0, stream>>>((ushort*)d_out, out_size);
    return;
  }

  // ---- probes + CSR ----
  k_probes<<<1, 256, 0, stream>>>((const uint*)ei_raw, (const uint*)x_raw, iflag, fflag);
  k_canon<<<(N + 255)/256, 256, 0, stream>>>(ba_raw, iflag, batch2, N);
  hipMemsetAsync(deg, 0, memset_bytes, stream);
  k_count<<<(E + 255)/256, 256, 0, stream>>>(ei_raw, iflag, deg, E, N);
  k_scan<<<1, 1024, 0, stream>>>(deg, rp, N);
  k_fill<<<(E + 255)/256, 256, 0, stream>>>(ei_raw, iflag, rp, fill, cpair, E, N);

  // ---- batched weight conversion (w1 x3, w2 x3, ne_w) ----
  CvtTab ct; ct.nseg = 7;
  const void* csrcs[7] = {d_in[8], d_in[16], d_in[24], d_in[10], d_in[18], d_in[26], d_in[6]};
  ushort* cdsts[7]     = {w1c[0],  w1c[1],   w1c[2],   w2c[0],   w2c[1],   w2c[2],   new_c};
  const int cns[7]     = {w1n[0],  w1n[1],   w1n[2],   w2n[0],   w2n[1],   w2n[2],   8192};
  int bacc = 0;
  for (int i = 0; i < 7; i++){
    ct.src[i] = csrcs[i]; ct.dst[i] = cdsts[i]; ct.n[i] = cns[i];
    ct.bstart[i] = bacc; bacc += (cns[i] + 8191)/8192;
  }
  k_cvt_batch<<<bacc, 256, 0, stream>>>(ct, fflag);

  // ---- small vectors packed ----
  SmallTab tab;
  int scount = 0, spos = 0;
  auto addsmall = [&](int di, int n)->int{
    int p = spos;
    tab.src[scount] = d_in[di]; tab.doff[scount] = spos; tab.n[scount] = n;
    spos += n; scount++;
    return p;
  };
  int pos_eew  = addsmall(4, 128);
  int pos_eeb  = addsmall(5, 16);
  int pos_neb  = addsmall(7, 256);
  int pos_b1[3], pos_b2[3], pos_g[3], pos_bb[3], pos_m[3], pos_v[3];
  const int b1n[3] = {512,512,256}, b2n[3] = {256,256,128}, bnn[3] = {256,256,128};
  for (int i = 0; i < 3; i++){
    int di = 8 + 8*i;
    pos_b1[i] = addsmall(di+1, b1n[i]);
    pos_b2[i] = addsmall(di+3, b2n[i]);
    pos_g[i]  = addsmall(di+4, bnn[i]);
    pos_bb[i] = addsmall(di+5, bnn[i]);
    pos_m[i]  = addsmall(di+6, bnn[i]);
    pos_v[i]  = addsmall(di+7, bnn[i]);
  }
  int pos_fcw = addsmall(32, 12*128);
  int pos_fcb = addsmall(33, 12);
  k_cvt_small<<<scount, 256, 0, stream>>>(tab, fflag, smallp, scount);

  // ---- encoders ----
  k_edge_enc<<<(E + 255)/256, 256, 0, stream>>>(ea_raw, smallp + pos_eew, smallp + pos_eeb, fflag, e_h32, E);
  k_node_enc<<<N, 256, 0, stream>>>(x_raw, new_c, smallp + pos_neb, fflag, h, N);

  // ---- 3 conv layers ----
  const int Cch[3] = {512, 512, 256};
  const int Od[3]  = {256, 256, 128};
  for (int i = 0; i < 3; i++){
    dim3 g1((N + 127)/128, 2*(Cch[i]/128));
    k_gemm_pq_lds<<<g1, 256, 0, stream>>>(h, w1c[i], N, Cch[i], PM, Q);
    dim3 gm((N + 3)/4);
    if (i < 2) k_msg4<512><<<gm, 256, 0, stream>>>(PM, Q, e_h32, w1c[i], smallp + pos_b1[i], rp, cpair, PM, N);
    else       k_msg4<256><<<gm, 128, 0, stream>>>(PM, Q, e_h32, w1c[i], smallp + pos_b1[i], rp, cpair, PM, N);
    dim3 g2((N + 127)/128, Od[i]/128);
    k_gemm_bn_lds<<<g2, 256, 0, stream>>>(PM, Cch[i], w2c[i], Cch[i], N, Od[i], Cch[i],
                                          smallp + pos_b2[i], smallp + pos_g[i], smallp + pos_bb[i],
                                          smallp + pos_m[i],  smallp + pos_v[i], rp, h);
  }

  // ---- mean pool + FC + sigmoid ----
  k_pool<<<G, 128, 0, stream>>>(h, batch2, smallp + pos_fcw, smallp + pos_fcb, fflag, d_out, N);
}

// Round 10
// 516.160 us; speedup vs baseline: 1.5988x; 1.0333x over previous
//
// GCNTox21 fused pipeline — MI355X/gfx950.  R10: (1) k_gemm_bn -> 64x128
// tiles (313-block grid; old 128x128 gave only 157-314 blocks = half the CUs
// idle); (2) k_msg4 -> 2 nodes/block (2x waves for latency cover; core loop
// untouched); (3) node_enc 4 nodes/block.  pq GEMM + everything else = R9.
// Math (exact algebraic refactor):
//   P = h@w1[:,:256].T, Q = h@w1[:,256:512].T  (node GEMMs, MFMA bf16)
//   u_e = relu(P[dst] + Q[src] + e_h[e]@w1[:,512:].T + b1)
//   mean_u[n] = mean_{e:dst=n} u_e             (CSR over dst, built once)
//   h' = relu(BN(mean_u@w2.T + b2)), deg==0 rows -> BN(0)
//   out = sigmoid(mean_pool(h)@fc.T + fc_b)
#include <hip/hip_runtime.h>
#include <hip/hip_bf16.h>

typedef unsigned int  uint;
typedef unsigned short ushort;
typedef float  f32x2  __attribute__((ext_vector_type(2)));
typedef float  f32x4  __attribute__((ext_vector_type(4)));
typedef __bf16 bf16x8 __attribute__((ext_vector_type(8)));

#define DEV static __device__ __forceinline__

DEV float  b2f(ushort b){ return __uint_as_float(((uint)b) << 16); }
DEV float  lo2f(uint u){ return __uint_as_float(u << 16); }
DEV float  hi2f(uint u){ return __uint_as_float(u & 0xffff0000u); }
DEV ushort f2b(float f){           // RNE float->bf16
  uint u = __float_as_uint(f);
  u += 0x7fffu + ((u >> 16) & 1u);
  return (ushort)(u >> 16);
}
DEV uint pk2(float a, float b){ return (uint)f2b(a) | ((uint)f2b(b) << 16); }
DEV void unpack8(uint4 v, float* f){
  f[0]=lo2f(v.x); f[1]=hi2f(v.x); f[2]=lo2f(v.y); f[3]=hi2f(v.y);
  f[4]=lo2f(v.z); f[5]=hi2f(v.z); f[6]=lo2f(v.w); f[7]=hi2f(v.w);
}
DEV int ld_idx(const void* p, int flag, long long i){
  return flag ? ((const int*)p)[i] : (int)((const long long*)p)[i];
}
DEV int clampi(int v, int lo, int hi){ return v < lo ? lo : (v > hi ? hi : v); }

// async 16B global -> LDS (DMA).  LDS dest = wave-uniform base + lane*16.
DEV void ld16(const ushort* g, ushort* l){
  __builtin_amdgcn_global_load_lds(
      (const __attribute__((address_space(1))) void*)g,
      (__attribute__((address_space(3))) void*)l, 16, 0, 0);
}

// ---------- merged probes ----------
__global__ void k_probes(const uint* __restrict__ ei, const uint* __restrict__ xw,
                         int* __restrict__ iflag, int* __restrict__ fflag){
  __shared__ int anyI, cntF;
  if (threadIdx.x == 0){ anyI = 0; cntF = 0; }
  __syncthreads();
  int li = 0, lc = 0;
  for (int i = threadIdx.x; i < 1024; i += 256){
    if (ei[2*i + 1] != 0u) li = 1;            // int64 => odd words all 0
    float f = fabsf(__uint_as_float(xw[i]));  // fp32 N(0,1) words decode sane
    if (f > 1e-6f && f < 1e6f) lc++;
  }
  if (li) atomicOr(&anyI, 1);
  atomicAdd(&cntF, lc);
  __syncthreads();
  if (threadIdx.x == 0){ *iflag = anyI; *fflag = (2*cntF > 1024) ? 1 : 0; }
}

// ---------- canonicalization ----------
__global__ __launch_bounds__(256) void k_canon(const void* __restrict__ src,
    const int* __restrict__ flag, int* __restrict__ out, int n){
  int i = blockIdx.x*256 + threadIdx.x;
  if (i >= n) return;
  out[i] = ld_idx(src, *flag, i);
}

struct CvtTab { const void* src[8]; ushort* dst[8]; int n[8]; int bstart[8]; int nseg; };
__global__ __launch_bounds__(256) void k_cvt_batch(CvtTab tab, const int* __restrict__ flag){
  int b = blockIdx.x;
  int s = tab.nseg - 1;
  for (int i = 1; i < tab.nseg; i++) if (b < tab.bstart[i]){ s = i - 1; break; }
  int rel = b - tab.bstart[s];
  const void* sp = tab.src[s];
  ushort* d = tab.dst[s];
  int f = *flag;
  int end = tab.n[s]; int cap = rel*8192 + 8192; if (cap < end) end = cap;
  for (int i = rel*8192 + threadIdx.x; i < end; i += 256)
    d[i] = f ? f2b(((const float*)sp)[i]) : ((const ushort*)sp)[i];
}

struct SmallTab { const void* src[24]; int doff[24]; int n[24]; };
__global__ __launch_bounds__(256) void k_cvt_small(SmallTab tab, const int* __restrict__ flag,
    ushort* __restrict__ base, int cnt){
  int b = blockIdx.x;
  if (b >= cnt) return;
  int f = *flag;
  const void* s = tab.src[b];
  ushort* d = base + tab.doff[b];
  for (int i = threadIdx.x; i < tab.n[b]; i += 256)
    d[i] = f ? f2b(((const float*)s)[i]) : ((const ushort*)s)[i];
}

// ---------- CSR build over dst ----------
__global__ __launch_bounds__(256) void k_count(const void* __restrict__ ei,
    const int* __restrict__ flag, int* __restrict__ cnt, int E, int N){
  int e = blockIdx.x*256 + threadIdx.x;
  if (e >= E) return;
  int d = clampi(ld_idx(ei, *flag, (long long)E + e), 0, N-1);
  atomicAdd(&cnt[d], 1);
}

__global__ __launch_bounds__(1024) void k_scan(const int* __restrict__ deg, int* __restrict__ rp, int n){
  __shared__ int part[1024];
  int t = threadIdx.x;
  int chunk = (n + 1023) >> 10;
  int base = t * chunk;
  int s = 0;
  for (int i = 0; i < chunk; i++){ int j = base + i; if (j < n) s += deg[j]; }
  part[t] = s;
  __syncthreads();
  for (int off = 1; off < 1024; off <<= 1){
    int v = (t >= off) ? part[t - off] : 0;
    __syncthreads();
    part[t] += v;
    __syncthreads();
  }
  int run = part[t] - s;
  for (int i = 0; i < chunk; i++){ int j = base + i; if (j < n){ rp[j] = run; run += deg[j]; } }
  if (t == 1023) rp[n] = part[1023];
}

__global__ __launch_bounds__(256) void k_fill(const void* __restrict__ ei,
    const int* __restrict__ flag, const int* __restrict__ rp, int* __restrict__ fill,
    int2* __restrict__ cpair, int E, int N){
  int e = blockIdx.x*256 + threadIdx.x;
  if (e >= E) return;
  int f = *flag;
  int s = clampi(ld_idx(ei, f, e), 0, N-1);
  int d = clampi(ld_idx(ei, f, (long long)E + e), 0, N-1);
  int pos = clampi(rp[d] + atomicAdd(&fill[d], 1), 0, E-1);
  cpair[pos] = make_int2(s, e);
}

// ---------- encoders ----------
__global__ __launch_bounds__(256) void k_edge_enc(const void* __restrict__ ea,
    const ushort* __restrict__ w, const ushort* __restrict__ b,
    const int* __restrict__ fflag, float* __restrict__ eh, int E){
  __shared__ float ws[128];
  __shared__ float bs[16];
  int t = threadIdx.x;
  if (t < 128) ws[t] = b2f(w[t]);
  if (t < 16)  bs[t] = b2f(b[t]);
  int f = *fflag;
  __syncthreads();
  int e = blockIdx.x*256 + t;
  if (e >= E) return;
  float a[8];
  if (f){
    const float4* ap = (const float4*)((const float*)ea + (size_t)e*8);
    float4 v0 = ap[0], v1 = ap[1];
    a[0]=v0.x; a[1]=v0.y; a[2]=v0.z; a[3]=v0.w;
    a[4]=v1.x; a[5]=v1.y; a[6]=v1.z; a[7]=v1.w;
  } else {
    uint4 av = *(const uint4*)((const ushort*)ea + (size_t)e*8);
    unpack8(av, a);
  }
  float o[16];
  #pragma unroll
  for (int c = 0; c < 16; c++){
    float s = bs[c];
    #pragma unroll
    for (int j = 0; j < 8; j++) s += a[j]*ws[c*8+j];
    o[c] = fmaxf(s, 0.f);
  }
  f32x4* op = (f32x4*)(eh + (size_t)e*16);
  #pragma unroll
  for (int q4 = 0; q4 < 4; q4++){
    f32x4 v = {o[q4*4+0], o[q4*4+1], o[q4*4+2], o[q4*4+3]};
    op[q4] = v;
  }
}

// 4 nodes/block: w row t loaded once, x rows staged in LDS
__global__ __launch_bounds__(256) void k_node_enc(const void* __restrict__ x,
    const ushort* __restrict__ w, const ushort* __restrict__ b,
    const int* __restrict__ fflag, ushort* __restrict__ h, int N){
  __shared__ float xs[4][32];
  int nb = blockIdx.x*4, t = threadIdx.x;
  int f = *fflag;
  if (t < 128){
    int ni = t >> 5, ci = t & 31;
    int n = nb + ni; if (n >= N) n = N - 1;
    xs[ni][ci] = f ? ((const float*)x)[(size_t)n*32 + ci]
                   : b2f(((const ushort*)x)[(size_t)n*32 + ci]);
  }
  __syncthreads();
  const uint4* wp = (const uint4*)(w + (size_t)t*32);
  float wr[32];
  unpack8(wp[0], wr); unpack8(wp[1], wr+8); unpack8(wp[2], wr+16); unpack8(wp[3], wr+24);
  float bv = b2f(b[t]);
  #pragma unroll
  for (int ni = 0; ni < 4; ni++){
    int n = nb + ni;
    if (n >= N) break;
    float s = bv;
    #pragma unroll
    for (int k = 0; k < 32; k++) s += xs[ni][k]*wr[k];
    h[(size_t)n*256 + t] = f2b(fmaxf(s, 0.f));
  }
}

// ---------- LDS-staged 128x128 GEMM: P/Q producer (R9, unchanged) ----------
__global__ __launch_bounds__(256) void k_gemm_pq_lds(const ushort* __restrict__ A,
    const ushort* __restrict__ w1, int M, int Nc,
    ushort* __restrict__ P, ushort* __restrict__ Q){
  __shared__ ushort As[128*32];
  __shared__ ushort Bs[128*32];
  const int t = threadIdx.x;
  const int lane = t & 63;
  const int wv = t >> 6;
  const int m0 = blockIdx.x*128;
  const int yc = Nc >> 7;
  const int isQ = (int)blockIdx.y >= yc;
  const int n0 = (isQ ? blockIdx.y - yc : blockIdx.y)*128;
  const ushort* W = w1 + (isQ ? 256 : 0);
  ushort* C = isQ ? Q : P;
  const int lr = lane & 15;
  const int qq = lane >> 4;
  int srow0 = t >> 2,         sq0 = t & 3;
  int srow1 = (256 + t) >> 2, sq1 = t & 3;
  int ga0 = m0 + srow0; if (ga0 >= M) ga0 = M - 1;
  int ga1 = m0 + srow1; if (ga1 >= M) ga1 = M - 1;
  f32x4 acc[2][8];
  #pragma unroll
  for (int f = 0; f < 2; f++)
    #pragma unroll
    for (int j = 0; j < 8; j++) acc[f][j] = {0.f,0.f,0.f,0.f};
  for (int k0 = 0; k0 < 256; k0 += 32){
    ld16(A + (size_t)ga0*256 + k0 + sq0*8, &As[(size_t)t*8]);
    ld16(A + (size_t)ga1*256 + k0 + sq1*8, &As[(size_t)(256+t)*8]);
    ld16(W + (size_t)(n0 + srow0)*528 + k0 + sq0*8, &Bs[(size_t)t*8]);
    ld16(W + (size_t)(n0 + srow1)*528 + k0 + sq1*8, &Bs[(size_t)(256+t)*8]);
    __syncthreads();
    bf16x8 a0 = *(const bf16x8*)&As[(wv*32 + lr)*32 + qq*8];
    bf16x8 a1 = *(const bf16x8*)&As[(wv*32 + 16 + lr)*32 + qq*8];
    #pragma unroll
    for (int j = 0; j < 8; j++){
      bf16x8 b = *(const bf16x8*)&Bs[(j*16 + lr)*32 + qq*8];
      acc[0][j] = __builtin_amdgcn_mfma_f32_16x16x32_bf16(a0, b, acc[0][j], 0, 0, 0);
      acc[1][j] = __builtin_amdgcn_mfma_f32_16x16x32_bf16(a1, b, acc[1][j], 0, 0, 0);
    }
    __syncthreads();
  }
  #pragma unroll
  for (int f = 0; f < 2; f++){
    #pragma unroll
    for (int r = 0; r < 4; r++){
      int row = m0 + wv*32 + f*16 + qq*4 + r;
      if (row >= M) continue;
      #pragma unroll
      for (int j = 0; j < 8; j++)
        C[(size_t)row*Nc + n0 + j*16 + lr] = f2b(acc[f][j][r]);
    }
  }
}

// ---------- LDS-staged 64x128 GEMM + bias + deg-mask + BN + relu ----------
// Smaller tile => grid 313x(Od/128): full CU coverage for the skinny GEMM2.
// Wave wv: rows [16wv,+16) x 128 cols; per K-step 1 a + 8 b ds_reads, 8 MFMA.
__global__ __launch_bounds__(256) void k_gemm_bn64(const ushort* __restrict__ A, int lda,
    const ushort* __restrict__ W, int ldb, int M, int Nc, int K,
    const ushort* __restrict__ bias, const ushort* __restrict__ g, const ushort* __restrict__ bb,
    const ushort* __restrict__ rm, const ushort* __restrict__ rv,
    const int* __restrict__ rp, ushort* __restrict__ H){
  __shared__ ushort As[64*32];
  __shared__ ushort Bs[128*32];
  const int t = threadIdx.x;
  const int lane = t & 63;
  const int wv = t >> 6;
  const int m0 = blockIdx.x*64;
  const int n0 = blockIdx.y*128;
  const int lr = lane & 15;
  const int qq = lane >> 4;
  int srowA = t >> 2, sqA = t & 3;             // 64 rows x 4 chunks
  int ga = m0 + srowA; if (ga >= M) ga = M - 1;
  int srowB0 = t >> 2,        srowB1 = 64 + (t >> 2);
  f32x4 acc[8];
  #pragma unroll
  for (int j = 0; j < 8; j++) acc[j] = {0.f,0.f,0.f,0.f};
  for (int k0 = 0; k0 < K; k0 += 32){
    ld16(A + (size_t)ga*lda + k0 + sqA*8, &As[(size_t)t*8]);
    ld16(W + (size_t)(n0 + srowB0)*ldb + k0 + sqA*8, &Bs[(size_t)t*8]);
    ld16(W + (size_t)(n0 + srowB1)*ldb + k0 + sqA*8, &Bs[(size_t)(256+t)*8]);
    __syncthreads();
    bf16x8 a = *(const bf16x8*)&As[(wv*16 + lr)*32 + qq*8];
    #pragma unroll
    for (int j = 0; j < 8; j++){
      bf16x8 b = *(const bf16x8*)&Bs[(j*16 + lr)*32 + qq*8];
      acc[j] = __builtin_amdgcn_mfma_f32_16x16x32_bf16(a, b, acc[j], 0, 0, 0);
    }
    __syncthreads();
  }
  float bi[8], sc[8], sh[8];
  #pragma unroll
  for (int j = 0; j < 8; j++){
    int col = n0 + j*16 + lr;
    bi[j] = b2f(bias[col]);
    sc[j] = b2f(g[col]) * rsqrtf(b2f(rv[col]) + 1e-5f);
    sh[j] = b2f(bb[col]) - b2f(rm[col]) * sc[j];
  }
  #pragma unroll
  for (int r = 0; r < 4; r++){
    int row = m0 + wv*16 + qq*4 + r;
    if (row >= M) continue;
    int empty = (rp[row+1] - rp[row] == 0);
    #pragma unroll
    for (int j = 0; j < 8; j++){
      float v = acc[j][r] + bi[j];
      if (empty) v = 0.f;
      H[(size_t)row*Nc + n0 + j*16 + lr] = f2b(fmaxf(v*sc[j] + sh[j], 0.f));
    }
  }
}

// ---------- per-node edge aggregation (R6 core, 2 nodes/block) ----------
// NO barriers/LDS; thread t owns channels {2t,2t+1}; 2-edge ILP unroll.
// MU may alias P (read-before-write).  2 nodes/block => 2x wave parallelism.
template<int C>
__global__ __launch_bounds__(256) void k_msg4(const ushort* P, const ushort* __restrict__ Q,
    const float* __restrict__ eh, const ushort* __restrict__ w1, const ushort* __restrict__ b1,
    const int* __restrict__ rp, const int2* __restrict__ cpair,
    ushort* MU, int N){
  int t = threadIdx.x;
  int c0 = t*2;
  f32x2 wc[16];
  {
    float a0[16], a1[16];
    const uint4* wp0 = (const uint4*)(w1 + (size_t)c0*528 + 512);
    const uint4* wp1 = (const uint4*)(w1 + (size_t)(c0+1)*528 + 512);
    unpack8(wp0[0], a0); unpack8(wp0[1], a0+8);
    unpack8(wp1[0], a1); unpack8(wp1[1], a1+8);
    #pragma unroll
    for (int j = 0; j < 16; j++){ wc[j].x = a0[j]; wc[j].y = a1[j]; }
  }
  uint bw = *(const uint*)(b1 + c0);
  f32x2 b1v = { lo2f(bw), hi2f(bw) };
  int nb = blockIdx.x*2;
  int ne = nb + 2; if (ne > N) ne = N;
  for (int n = nb; n < ne; n++){
    const int i0 = rp[n], i1 = rp[n+1];
    uint pw = *(const uint*)(P + (size_t)n*C + c0);
    f32x2 pre = { lo2f(pw) + b1v.x, hi2f(pw) + b1v.y };
    f32x2 acc0 = {0.f, 0.f}, acc1 = {0.f, 0.f};
    int i = i0;
    for (; i + 2 <= i1; i += 2){
      int2 p0 = cpair[i];
      int2 p1 = cpair[i+1];
      uint qw0 = *(const uint*)(Q + (size_t)p0.x*C + c0);
      uint qw1 = *(const uint*)(Q + (size_t)p1.x*C + c0);
      const f32x4* e0p = (const f32x4*)(eh + (size_t)p0.y*16);
      const f32x4* e1p = (const f32x4*)(eh + (size_t)p1.y*16);
      f32x4 ea0 = e0p[0], ea1 = e0p[1], ea2 = e0p[2], ea3 = e0p[3];
      f32x4 eb0 = e1p[0], eb1 = e1p[1], eb2 = e1p[2], eb3 = e1p[3];
      float ef0[16] = {ea0.x,ea0.y,ea0.z,ea0.w, ea1.x,ea1.y,ea1.z,ea1.w,
                       ea2.x,ea2.y,ea2.z,ea2.w, ea3.x,ea3.y,ea3.z,ea3.w};
      float ef1[16] = {eb0.x,eb0.y,eb0.z,eb0.w, eb1.x,eb1.y,eb1.z,eb1.w,
                       eb2.x,eb2.y,eb2.z,eb2.w, eb3.x,eb3.y,eb3.z,eb3.w};
      f32x2 d0 = { pre.x + lo2f(qw0), pre.y + hi2f(qw0) };
      f32x2 d1 = { pre.x + lo2f(qw1), pre.y + hi2f(qw1) };
      #pragma unroll
      for (int j = 0; j < 16; j++){
        f32x2 e0v = {ef0[j], ef0[j]};
        f32x2 e1v = {ef1[j], ef1[j]};
        d0 += wc[j] * e0v;
        d1 += wc[j] * e1v;
      }
      acc0.x += fmaxf(d0.x, 0.f); acc0.y += fmaxf(d0.y, 0.f);
      acc1.x += fmaxf(d1.x, 0.f); acc1.y += fmaxf(d1.y, 0.f);
    }
    if (i < i1){
      int2 p0 = cpair[i];
      uint qw0 = *(const uint*)(Q + (size_t)p0.x*C + c0);
      const f32x4* e0p = (const f32x4*)(eh + (size_t)p0.y*16);
      f32x4 ea0 = e0p[0], ea1 = e0p[1], ea2 = e0p[2], ea3 = e0p[3];
      float ef0[16] = {ea0.x,ea0.y,ea0.z,ea0.w, ea1.x,ea1.y,ea1.z,ea1.w,
                       ea2.x,ea2.y,ea2.z,ea2.w, ea3.x,ea3.y,ea3.z,ea3.w};
      f32x2 d0 = { pre.x + lo2f(qw0), pre.y + hi2f(qw0) };
      #pragma unroll
      for (int j = 0; j < 16; j++){
        f32x2 e0v = {ef0[j], ef0[j]};
        d0 += wc[j] * e0v;
      }
      acc0.x += fmaxf(d0.x, 0.f); acc0.y += fmaxf(d0.y, 0.f);
    }
    int cnt = i1 - i0;
    float inv = (cnt > 0) ? 1.f/(float)cnt : 0.f;
    *(uint*)(MU + (size_t)n*C + c0) = pk2((acc0.x + acc1.x)*inv, (acc0.y + acc1.y)*inv);
  }
}

// ---------- pooling + FC + sigmoid ----------
__global__ __launch_bounds__(128) void k_pool(const ushort* __restrict__ h, const int* __restrict__ batch,
    const ushort* __restrict__ fw, const ushort* __restrict__ fb,
    const int* __restrict__ fflag, void* __restrict__ out, int N){
  int g = blockIdx.x, t = threadIdx.x;
  int lo = 0, hi = N;
  while (lo < hi){ int mid = (lo+hi) >> 1; if (batch[mid] <  g) lo = mid+1; else hi = mid; }
  int s0 = lo;
  hi = N;
  while (lo < hi){ int mid = (lo+hi) >> 1; if (batch[mid] <= g) lo = mid+1; else hi = mid; }
  int s1 = lo;
  float s = 0.f;
  for (int i = s0; i < s1; i++) s += b2f(h[(size_t)i*128 + t]);
  int cnt = s1 - s0;
  __shared__ float ps[128];
  ps[t] = s / (float)(cnt > 0 ? cnt : 1);
  __syncthreads();
  if (t < 12){
    float z = b2f(fb[t]);
    for (int j = 0; j < 128; j++) z += ps[j]*b2f(fw[t*128 + j]);
    float r = 1.f/(1.f + expf(-z));
    if (*fflag) ((float*)out)[g*12 + t] = r;
    else        ((ushort*)out)[g*12 + t] = f2b(r);
  }
}

__global__ __launch_bounds__(256) void k_sentinel(ushort* __restrict__ out, int n){
  int i = blockIdx.x*256 + threadIdx.x;
  if (i < n) out[i] = 0x3F00;
}

extern "C" void kernel_launch(void* const* d_in, const int* in_sizes, int n_in,
                              void* d_out, int out_size, void* d_ws, size_t ws_size,
                              hipStream_t stream){
  const void* x_raw   = d_in[0];
  const void* ei_raw  = d_in[1];
  const void* ea_raw  = d_in[2];
  const void* ba_raw  = d_in[3];
  (void)n_in;

  const int N = in_sizes[3];        // 20000
  const int E = in_sizes[1] / 2;    // 200000
  const int G = out_size / 12;      // 512

  // ---- workspace plan ----
  char* base = (char*)d_ws;
  size_t off = 0;
  auto alloc = [&](size_t bytes)->char*{
    char* p = base + off;
    off = (off + bytes + 255) & ~(size_t)255;
    return p;
  };
  int* iflag    = (int*)alloc(256);
  int* fflag    = (int*)alloc(256);
  int* deg      = (int*)alloc((size_t)N*4);
  int* fill     = (int*)alloc((size_t)N*4);   // contiguous after deg (one memset)
  size_t memset_bytes = (size_t)((char*)fill - (char*)deg) + (size_t)N*4;
  int* rp       = (int*)alloc((size_t)(N+1)*4);
  int* batch2   = (int*)alloc((size_t)N*4);
  int2* cpair   = (int2*)alloc((size_t)E*8);
  ushort* new_c = (ushort*)alloc(8192*2);
  ushort* w1c[3], *w2c[3];
  const int w1n[3] = {512*528, 512*528, 256*528};
  const int w2n[3] = {256*512, 256*512, 128*256};
  for (int i = 0; i < 3; i++) w1c[i] = (ushort*)alloc((size_t)w1n[i]*2);
  for (int i = 0; i < 3; i++) w2c[i] = (ushort*)alloc((size_t)w2n[i]*2);
  ushort* smallp = (ushort*)alloc(8192*2);
  float*  e_h32 = (float*)alloc((size_t)E*16*4);    // 12.8 MB, pre-unpacked f32
  ushort* h     = (ushort*)alloc((size_t)N*256*2);
  ushort* Q     = (ushort*)alloc((size_t)N*512*2);
  ushort* PM    = (ushort*)alloc((size_t)N*512*2);

  if (off > ws_size){
    k_sentinel<<<(out_size + 255)/256, 256, 0, stream>>>((ushort*)d_out, out_size);
    return;
  }

  // ---- probes + CSR ----
  k_probes<<<1, 256, 0, stream>>>((const uint*)ei_raw, (const uint*)x_raw, iflag, fflag);
  k_canon<<<(N + 255)/256, 256, 0, stream>>>(ba_raw, iflag, batch2, N);
  hipMemsetAsync(deg, 0, memset_bytes, stream);
  k_count<<<(E + 255)/256, 256, 0, stream>>>(ei_raw, iflag, deg, E, N);
  k_scan<<<1, 1024, 0, stream>>>(deg, rp, N);
  k_fill<<<(E + 255)/256, 256, 0, stream>>>(ei_raw, iflag, rp, fill, cpair, E, N);

  // ---- batched weight conversion (w1 x3, w2 x3, ne_w) ----
  CvtTab ct; ct.nseg = 7;
  const void* csrcs[7] = {d_in[8], d_in[16], d_in[24], d_in[10], d_in[18], d_in[26], d_in[6]};
  ushort* cdsts[7]     = {w1c[0],  w1c[1],   w1c[2],   w2c[0],   w2c[1],   w2c[2],   new_c};
  const int cns[7]     = {w1n[0],  w1n[1],   w1n[2],   w2n[0],   w2n[1],   w2n[2],   8192};
  int bacc = 0;
  for (int i = 0; i < 7; i++){
    ct.src[i] = csrcs[i]; ct.dst[i] = cdsts[i]; ct.n[i] = cns[i];
    ct.bstart[i] = bacc; bacc += (cns[i] + 8191)/8192;
  }
  k_cvt_batch<<<bacc, 256, 0, stream>>>(ct, fflag);

  // ---- small vectors packed ----
  SmallTab tab;
  int scount = 0, spos = 0;
  auto addsmall = [&](int di, int n)->int{
    int p = spos;
    tab.src[scount] = d_in[di]; tab.doff[scount] = spos; tab.n[scount] = n;
    spos += n; scount++;
    return p;
  };
  int pos_eew  = addsmall(4, 128);
  int pos_eeb  = addsmall(5, 16);
  int pos_neb  = addsmall(7, 256);
  int pos_b1[3], pos_b2[3], pos_g[3], pos_bb[3], pos_m[3], pos_v[3];
  const int b1n[3] = {512,512,256}, b2n[3] = {256,256,128}, bnn[3] = {256,256,128};
  for (int i = 0; i < 3; i++){
    int di = 8 + 8*i;
    pos_b1[i] = addsmall(di+1, b1n[i]);
    pos_b2[i] = addsmall(di+3, b2n[i]);
    pos_g[i]  = addsmall(di+4, bnn[i]);
    pos_bb[i] = addsmall(di+5, bnn[i]);
    pos_m[i]  = addsmall(di+6, bnn[i]);
    pos_v[i]  = addsmall(di+7, bnn[i]);
  }
  int pos_fcw = addsmall(32, 12*128);
  int pos_fcb = addsmall(33, 12);
  k_cvt_small<<<scount, 256, 0, stream>>>(tab, fflag, smallp, scount);

  // ---- encoders ----
  k_edge_enc<<<(E + 255)/256, 256, 0, stream>>>(ea_raw, smallp + pos_eew, smallp + pos_eeb, fflag, e_h32, E);
  k_node_enc<<<(N + 3)/4, 256, 0, stream>>>(x_raw, new_c, smallp + pos_neb, fflag, h, N);

  // ---- 3 conv layers ----
  const int Cch[3] = {512, 512, 256};
  const int Od[3]  = {256, 256, 128};
  for (int i = 0; i < 3; i++){
    dim3 g1((N + 127)/128, 2*(Cch[i]/128));
    k_gemm_pq_lds<<<g1, 256, 0, stream>>>(h, w1c[i], N, Cch[i], PM, Q);
    dim3 gm((N + 1)/2);
    if (i < 2) k_msg4<512><<<gm, 256, 0, stream>>>(PM, Q, e_h32, w1c[i], smallp + pos_b1[i], rp, cpair, PM, N);
    else       k_msg4<256><<<gm, 128, 0, stream>>>(PM, Q, e_h32, w1c[i], smallp + pos_b1[i], rp, cpair, PM, N);
    dim3 g2((N + 63)/64, Od[i]/128 > 0 ? Od[i]/128 : 1);
    k_gemm_bn64<<<g2, 256, 0, stream>>>(PM, Cch[i], w2c[i], Cch[i], N, Od[i], Cch[i],
                                        smallp + pos_b2[i], smallp + pos_g[i], smallp + pos_bb[i],
                                        smallp + pos_m[i],  smallp + pos_v[i], rp, h);
  }

  // ---- mean pool + FC + sigmoid ----
  k_pool<<<G, 128, 0, stream>>>(h, batch2, smallp + pos_fcw, smallp + pos_fcb, fflag, d_out, N);
}